// Round 5
// baseline (437.624 us; speedup 1.0000x reference)
//
#include <hip/hip_runtime.h>
#include <hip/hip_bf16.h>

#define BB 16
#define NN 2048
#define FIN 256
#define FO 64

typedef __bf16 bf16x8 __attribute__((ext_vector_type(8)));
typedef float  f32x4  __attribute__((ext_vector_type(4)));
typedef int    i32x4  __attribute__((ext_vector_type(4)));
typedef unsigned int uint;

// ---------------- K1: h GEMM (MFMA bf16) + exact fp32 s_src/s_dst ------------
__global__ __launch_bounds__(256) void k1_gemm(
    const float* __restrict__ x, const float* __restrict__ weight,
    const float* __restrict__ w2,
    __bf16* __restrict__ hT, float* __restrict__ s_src, float* __restrict__ s_dst) {
    __shared__ __bf16 WtL[FO * 264];
    __shared__ float vsL[FIN], vdL[FIN];
    int t = threadIdx.x;
    {
        const float4* wr = (const float4*)(weight + t * FO);
        float a = 0.f, d = 0.f;
#pragma unroll
        for (int c = 0; c < 16; ++c) {
            float4 v = wr[c];
            int o = c * 4;
            WtL[(o + 0) * 264 + t] = (__bf16)v.x;
            WtL[(o + 1) * 264 + t] = (__bf16)v.y;
            WtL[(o + 2) * 264 + t] = (__bf16)v.z;
            WtL[(o + 3) * 264 + t] = (__bf16)v.w;
            a += v.x * w2[o] + v.y * w2[o + 1] + v.z * w2[o + 2] + v.w * w2[o + 3];
            d += v.x * w2[FO + o] + v.y * w2[FO + o + 1] +
                 v.z * w2[FO + o + 2] + v.w * w2[FO + o + 3];
        }
        vsL[t] = a;
        vdL[t] = d;
    }
    __syncthreads();

    int lane = threadIdx.x & 63, w = threadIdx.x >> 6;
    int quad = lane >> 4, m = lane & 15;
    int Rbase = blockIdx.x * 64 + w * 16;
    int R = Rbase + m;
    const float* xr = x + (long)R * FIN;

    f32x4 acc[4] = {};
    float ps = 0.f, pd = 0.f;

#pragma unroll
    for (int k0 = 0; k0 < FIN; k0 += 32) {
        int kb = k0 + quad * 8;
        float4 x0 = *(const float4*)(xr + kb);
        float4 x1 = *(const float4*)(xr + kb + 4);
        float4 u0 = *(const float4*)(vsL + kb);
        float4 u1 = *(const float4*)(vsL + kb + 4);
        float4 t0 = *(const float4*)(vdL + kb);
        float4 t1 = *(const float4*)(vdL + kb + 4);
        ps += x0.x * u0.x + x0.y * u0.y + x0.z * u0.z + x0.w * u0.w +
              x1.x * u1.x + x1.y * u1.y + x1.z * u1.z + x1.w * u1.w;
        pd += x0.x * t0.x + x0.y * t0.y + x0.z * t0.z + x0.w * t0.w +
              x1.x * t1.x + x1.y * t1.y + x1.z * t1.z + x1.w * t1.w;
        bf16x8 bf = {(__bf16)x0.x, (__bf16)x0.y, (__bf16)x0.z, (__bf16)x0.w,
                     (__bf16)x1.x, (__bf16)x1.y, (__bf16)x1.z, (__bf16)x1.w};
#pragma unroll
        for (int ot = 0; ot < 4; ++ot) {
            bf16x8 af = *(const bf16x8*)(WtL + (ot * 16 + m) * 264 + kb);
            acc[ot] = __builtin_amdgcn_mfma_f32_16x16x32_bf16(af, bf, acc[ot], 0, 0, 0);
        }
    }
    ps += __shfl_xor(ps, 16);
    ps += __shfl_xor(ps, 32);
    pd += __shfl_xor(pd, 16);
    pd += __shfl_xor(pd, 32);
    if (quad == 0) {
        s_src[R] = ps;
        s_dst[R] = pd;
    }
    int b = R >> 11;
    int nb = Rbase & (NN - 1);
#pragma unroll
    for (int ot = 0; ot < 4; ++ot) {
#pragma unroll
        for (int r = 0; r < 4; ++r) {
            int o = ot * 16 + quad * 4 + r;
            hT[((long)b * FO + o) * NN + nb + m] = (__bf16)acc[ot][r];
        }
    }
}

// ---------------- K2: fully fused adj-stream + masked-softmax + PV -----------
// grid = 16 b * 32 itiles = 512 blocks (2/CU); block = 4 waves; wave = 16 rows.
// Each lane packs ONLY its own mask bits (row rowbase+m, byte ks*4+quad) from
// adj directly — no pack kernel, no shfl routing. 4 groups: 32 independent nt
// dwordx4 loads each, fully unrolled so group g+1 loads overlap group g MFMAs.
// exp eliminated from inner loop: p = fmax(K*E_j, cM), E_j=exp(sd_j-mx) in LDS
// (per-wave redundant fill, zero barriers). Denominator via MFMA with ones.
__global__ __launch_bounds__(256, 2) void k2_attn(
    const int* __restrict__ adj, const float* __restrict__ s_src,
    const float* __restrict__ s_dst, const __bf16* __restrict__ hT,
    float* __restrict__ out) {
    __shared__ float EL[NN];  // exp(sd_j - mx), 8 KB
    int b = blockIdx.x >> 5;
    int i0 = (blockIdx.x & 31) << 6;
    int lane = threadIdx.x & 63, w = threadIdx.x >> 6;
    int quad = lane >> 4, m = lane & 15;
    int rowbase = i0 + w * 16;
    int row = rowbase + m;

    const float* sd = s_dst + b * NN;
    // wave max of s_dst (identical across waves -> consistent EL, no barrier)
    float mx = -3.0e38f;
    for (int j = lane; j < NN; j += 64) mx = fmaxf(mx, sd[j]);
#pragma unroll
    for (int off = 32; off >= 1; off >>= 1) mx = fmaxf(mx, __shfl_xor(mx, off));
    // per-wave redundant EL fill (benign same-value race across waves)
    for (int t = lane; t < NN; t += 64) EL[t] = __expf(sd[t] - mx);

    float ssr = s_src[b * NN + row];
    float T = ssr + mx;
    float M = fmaxf(T, 0.f);
    float K = __expf(fminf(T, 0.f));   // exp(T - M)
    float cM = __expf(-M);             // relu-floor value exp(0 - M)

    const int* adjrow = adj + ((long)(b * NN + row)) * NN;
    const __bf16* hTb = hT + (long)b * FO * NN;
    int q8 = quad * 8;

    f32x4 acc[4] = {};
    f32x4 accL = {};
    const bf16x8 ones = {(__bf16)1.f, (__bf16)1.f, (__bf16)1.f, (__bf16)1.f,
                         (__bf16)1.f, (__bf16)1.f, (__bf16)1.f, (__bf16)1.f};
    uint bw[16];

#pragma unroll
    for (int g = 0; g < 4; ++g) {
        // ---- pack group g: bits for ks = g*16 .. g*16+15 (32 nt loads) ----
#pragma unroll
        for (int ii = 0; ii < 4; ++ii) {
            int i = g * 4 + ii;
            uint bwv = 0;
#pragma unroll
            for (int j = 0; j < 4; ++j) {
                int ks = i * 4 + j;
                const i32x4* ap = (const i32x4*)(adjrow + ks * 32 + q8);
                i32x4 a0 = __builtin_nontemporal_load(ap);
                i32x4 a1 = __builtin_nontemporal_load(ap + 1);
                uint by = (uint)(a0.x > 0) | ((uint)(a0.y > 0) << 1) |
                          ((uint)(a0.z > 0) << 2) | ((uint)(a0.w > 0) << 3) |
                          ((uint)(a1.x > 0) << 4) | ((uint)(a1.y > 0) << 5) |
                          ((uint)(a1.z > 0) << 6) | ((uint)(a1.w > 0) << 7);
                bwv |= by << (8 * j);
            }
            bw[i] = bwv;
        }
        // ---- MFMA group g ----
#pragma unroll
        for (int u = 0; u < 16; ++u) {
            int ks = g * 16 + u;
            uint mb = (bw[g * 4 + (u >> 2)] >> ((u & 3) * 8)) & 0xffu;
            const float* ep = EL + ks * 32 + q8;
            float4 e0 = *(const float4*)ep;
            float4 e1 = *(const float4*)(ep + 4);
            float p0 = (mb & 1u)   ? fmaxf(K * e0.x, cM) : 0.f;
            float p1 = (mb & 2u)   ? fmaxf(K * e0.y, cM) : 0.f;
            float p2 = (mb & 4u)   ? fmaxf(K * e0.z, cM) : 0.f;
            float p3 = (mb & 8u)   ? fmaxf(K * e0.w, cM) : 0.f;
            float p4 = (mb & 16u)  ? fmaxf(K * e1.x, cM) : 0.f;
            float p5 = (mb & 32u)  ? fmaxf(K * e1.y, cM) : 0.f;
            float p6 = (mb & 64u)  ? fmaxf(K * e1.z, cM) : 0.f;
            float p7 = (mb & 128u) ? fmaxf(K * e1.w, cM) : 0.f;
            bf16x8 af = {(__bf16)p0, (__bf16)p1, (__bf16)p2, (__bf16)p3,
                         (__bf16)p4, (__bf16)p5, (__bf16)p6, (__bf16)p7};
            accL = __builtin_amdgcn_mfma_f32_16x16x32_bf16(af, ones, accL, 0, 0, 0);
            const __bf16* hb = hTb + ks * 32 + q8;
#pragma unroll
            for (int ot = 0; ot < 4; ++ot) {
                bf16x8 bf = *(const bf16x8*)(hb + (ot * 16 + m) * NN);
                acc[ot] = __builtin_amdgcn_mfma_f32_16x16x32_bf16(af, bf, acc[ot], 0, 0, 0);
            }
        }
    }

    // epilogue: D layout col=lane&15 (o), row=quad*4+r (i-local); accL[r]=denom
    float* outp = out + ((long)b * NN + rowbase) * FO;
#pragma unroll
    for (int r = 0; r < 4; ++r) {
        int orow = quad * 4 + r;
        float inv = 1.0f / accL[r];
#pragma unroll
        for (int ot = 0; ot < 4; ++ot) {
            outp[(long)orow * FO + ot * 16 + m] = acc[ot][r] * inv;
        }
    }
}

extern "C" void kernel_launch(void* const* d_in, const int* in_sizes, int n_in,
                              void* d_out, int out_size, void* d_ws, size_t ws_size,
                              hipStream_t stream) {
    const float* x      = (const float*)d_in[0];
    const int*   adj    = (const int*)d_in[1];
    const float* weight = (const float*)d_in[2];
    const float* w2     = (const float*)d_in[3];
    float* out = (float*)d_out;

    char* ws = (char*)d_ws;
    __bf16* hT   = (__bf16*)ws;                     // 4 MB
    float* s_src = (float*)(ws + 4194304);          // 128 KB
    float* s_dst = (float*)(ws + 4194304 + 131072); // 128 KB

    k1_gemm<<<512, 256, 0, stream>>>(x, weight, w2, hT, s_src, s_dst);
    k2_attn<<<512, 256, 0, stream>>>(adj, s_src, s_dst, hT, out);
}